// Round 1
// baseline (297.020 us; speedup 1.0000x reference)
//
#include <hip/hip_runtime.h>
#include <hip/hip_bf16.h>

#define DEV static __device__ __forceinline__

typedef __attribute__((ext_vector_type(4))) float f32x4;
typedef __attribute__((ext_vector_type(8))) short bf16x8;

DEV unsigned short f2bf(float f) {
  union { float f; unsigned u; } v; v.f = f;
  unsigned r = (v.u + 0x7fffu + ((v.u >> 16) & 1u)) >> 16;
  return (unsigned short)r;
}
DEV float bf2f(unsigned short u) {
  union { unsigned u; float f; } v; v.u = ((unsigned)u) << 16;
  return v.f;
}
DEV void gl_lds16(const unsigned short* g, unsigned short* l) {
  __builtin_amdgcn_global_load_lds(
      (const __attribute__((address_space(1))) void*)g,
      (__attribute__((address_space(3))) void*)l, 16, 0, 0);
}

// ---------------- cast fp32 -> bf16 (optionally into a wider row) ----------
__global__ void k_cast(const float* __restrict__ src, unsigned short* __restrict__ dst,
                       int cols, int ldd, int coloff, int n4) {
  int i = blockIdx.x * 256 + threadIdx.x;
  if (i >= n4) return;
  int idx = i * 4;
  int r = idx / cols, c = idx - r * cols;
  const float4 v = *(const float4*)(src + idx);
  union { unsigned short u[4]; uint2 p; } o;
  o.u[0] = f2bf(v.x); o.u[1] = f2bf(v.y); o.u[2] = f2bf(v.z); o.u[3] = f2bf(v.w);
  *(uint2*)(dst + (size_t)r * ldd + coloff + c) = o.p;
}

// ---------------- transpose + cast: dst[n*K + k] = bf16(src[k*N + n]) ------
__global__ void k_transpose(const float* __restrict__ src, unsigned short* __restrict__ dst,
                            int K, int N) {
  __shared__ float tile[32][33];
  const int n0 = blockIdx.x * 32, k0 = blockIdx.y * 32;
  const int tx = threadIdx.x & 31, ty = threadIdx.x >> 5;
#pragma unroll
  for (int i = 0; i < 4; i++)
    tile[ty + i * 8][tx] = src[(size_t)(k0 + ty + i * 8) * N + n0 + tx];
  __syncthreads();
#pragma unroll
  for (int i = 0; i < 4; i++)
    dst[(size_t)(n0 + ty + i * 8) * K + k0 + tx] = f2bf(tile[tx][ty + i * 8]);
}

// ---------------- GEMM: C[M,768] = A[M,K] @ Bt[768,K]^T + bias -------------
// 128x128 tile, BK=32, 4 waves (2x2), 16x16x32 bf16 MFMA, global_load_lds staging.
// EPI 0: bf16 out (ld 768), scaled              (q,k proj)
// EPI 1: scatter to vT[b][h][d][m]              (v proj)
// EPI 2: bf16 into concat right half            (out proj)
// EPI 3: sigmoid gate + final mix -> dout f32   (gate)
template <int EPI>
__global__ void k_gemm(const unsigned short* __restrict__ A, int lda,
                       const unsigned short* __restrict__ Bt, int ldb,
                       const float* __restrict__ bias, int K, float scale,
                       unsigned short* __restrict__ out0,
                       const unsigned short* __restrict__ concat_in,
                       const float* __restrict__ qy, float* __restrict__ dout) {
  __shared__ alignas(16) unsigned short Al[128 * 32];
  __shared__ alignas(16) unsigned short Bl[128 * 32];
  const int t = threadIdx.x;
  const int r0 = blockIdx.y * 128, c0 = blockIdx.x * 128;
  const int lane = t & 63, l15 = lane & 15, l4 = lane >> 4;
  const int wid = t >> 6, wr = wid >> 1, wc = wid & 1;

  f32x4 acc[4][4];
#pragma unroll
  for (int mi = 0; mi < 4; mi++)
#pragma unroll
    for (int ni = 0; ni < 4; ni++) acc[mi][ni] = (f32x4){0.f, 0.f, 0.f, 0.f};

  for (int k0 = 0; k0 < K; k0 += 32) {
#pragma unroll
    for (int p = 0; p < 2; p++) {
      const int flat = (p * 256 + t) * 8;
      const int row = flat >> 5, kk = flat & 31;
      gl_lds16(A + (size_t)(r0 + row) * lda + k0 + kk, &Al[flat]);
      gl_lds16(Bt + (size_t)(c0 + row) * ldb + k0 + kk, &Bl[flat]);
    }
    __syncthreads();
    bf16x8 af[4], bfr[4];
#pragma unroll
    for (int mi = 0; mi < 4; mi++)
      af[mi] = *(const bf16x8*)&Al[(wr * 64 + mi * 16 + l15) * 32 + l4 * 8];
#pragma unroll
    for (int ni = 0; ni < 4; ni++)
      bfr[ni] = *(const bf16x8*)&Bl[(wc * 64 + ni * 16 + l15) * 32 + l4 * 8];
#pragma unroll
    for (int mi = 0; mi < 4; mi++)
#pragma unroll
      for (int ni = 0; ni < 4; ni++)
        acc[mi][ni] = __builtin_amdgcn_mfma_f32_16x16x32_bf16(af[mi], bfr[ni], acc[mi][ni], 0, 0, 0);
    __syncthreads();
  }

#pragma unroll
  for (int ni = 0; ni < 4; ni++) {
    const int c = c0 + wc * 64 + ni * 16 + l15;
    const float bv = bias[c];
#pragma unroll
    for (int mi = 0; mi < 4; mi++) {
      const int rbase = r0 + wr * 64 + mi * 16 + l4 * 4;
#pragma unroll
      for (int i = 0; i < 4; i++) {
        const int r = rbase + i;
        const float val = (acc[mi][ni][i] + bv) * scale;
        if (EPI == 0) {
          out0[(size_t)r * 768 + c] = f2bf(val);
        } else if (EPI == 1) {
          const int b = r >> 9, m = r & 511;
          const int h = c >> 6, dd = c & 63;
          out0[(((size_t)(b * 12 + h)) * 64 + dd) * 512 + m] = f2bf(val);
        } else if (EPI == 2) {
          out0[(size_t)r * 1536 + 768 + c] = f2bf(val);
        } else {
          const float g = 1.f / (1.f + __expf(-val));
          const float o = bf2f(concat_in[(size_t)r * 1536 + 768 + c]);
          const float q = qy[(size_t)r * 768 + c];
          dout[(size_t)r * 768 + c] = g * o + (1.f - g) * q;
        }
      }
    }
  }
}

// ---------------- fused attention -----------------------------------------
// grid (32 s-tiles, 12 heads, 4 batch); 4 waves x 16 q-rows; M=512, Hd=64.
__global__ __launch_bounds__(256) void k_attn(
    const unsigned short* __restrict__ qbf,   // [B*S,768], pre-scaled by 1/8
    const unsigned short* __restrict__ kbf,   // [B*M,768]
    const unsigned short* __restrict__ vT,    // [B,H,64,512]
    const float* __restrict__ mscore,         // [B,512]
    unsigned short* __restrict__ aout) {      // [B*S,768]
  const int st = blockIdx.x, h = blockIdx.y, b = blockIdx.z;
  __shared__ float bias_s[512];
  __shared__ alignas(16) unsigned short P[4][16][520];
  const int t = threadIdx.x;
  for (int i = t; i < 512; i += 256) bias_s[i] = mscore[b * 512 + i];
  __syncthreads();
  const int wid = t >> 6, lane = t & 63, l15 = lane & 15, l4 = lane >> 4;
  const int srow = st * 64 + wid * 16;
  const unsigned short* qrow = qbf + ((size_t)(b * 2048 + srow + l15)) * 768 + h * 64;

  f32x4 acc[32];
#pragma unroll
  for (int i = 0; i < 32; i++) acc[i] = (f32x4){0.f, 0.f, 0.f, 0.f};

#pragma unroll
  for (int kb = 0; kb < 2; kb++) {
    const bf16x8 a = *(const bf16x8*)(qrow + kb * 32 + l4 * 8);
    const unsigned short* kp = kbf + ((size_t)b * 512) * 768 + h * 64 + kb * 32 + l4 * 8;
#pragma unroll
    for (int tt = 0; tt < 32; tt++) {
      const bf16x8 bb = *(const bf16x8*)(kp + (size_t)(tt * 16 + l15) * 768);
      acc[tt] = __builtin_amdgcn_mfma_f32_16x16x32_bf16(a, bb, acc[tt], 0, 0, 0);
    }
  }

  // softmax over m (rows are l4*4+i, cols spread over l15 x 32 tiles)
  float mx[4] = {-1e30f, -1e30f, -1e30f, -1e30f};
#pragma unroll
  for (int tt = 0; tt < 32; tt++) {
    const float bs = bias_s[tt * 16 + l15];
#pragma unroll
    for (int i = 0; i < 4; i++) { acc[tt][i] += bs; mx[i] = fmaxf(mx[i], acc[tt][i]); }
  }
#pragma unroll
  for (int d = 1; d < 16; d <<= 1)
#pragma unroll
    for (int i = 0; i < 4; i++) mx[i] = fmaxf(mx[i], __shfl_xor(mx[i], d));
  float sm[4] = {0.f, 0.f, 0.f, 0.f};
#pragma unroll
  for (int tt = 0; tt < 32; tt++)
#pragma unroll
    for (int i = 0; i < 4; i++) {
      const float p = __expf(acc[tt][i] - mx[i]);
      acc[tt][i] = p; sm[i] += p;
    }
#pragma unroll
  for (int d = 1; d < 16; d <<= 1)
#pragma unroll
    for (int i = 0; i < 4; i++) sm[i] += __shfl_xor(sm[i], d);
  float rs[4];
#pragma unroll
  for (int i = 0; i < 4; i++) rs[i] = 1.f / sm[i];

#pragma unroll
  for (int tt = 0; tt < 32; tt++)
#pragma unroll
    for (int i = 0; i < 4; i++)
      P[wid][l4 * 4 + i][tt * 16 + l15] = f2bf(acc[tt][i]);

  // PV: out[16 x 64] = P[16 x 512] @ V[512 x 64]
  f32x4 o[4];
#pragma unroll
  for (int i = 0; i < 4; i++) o[i] = (f32x4){0.f, 0.f, 0.f, 0.f};
  const unsigned short* vb = vT + ((size_t)(b * 12 + h)) * 64 * 512;
#pragma unroll
  for (int mk = 0; mk < 16; mk++) {
    const bf16x8 a = *(const bf16x8*)&P[wid][l15][mk * 32 + l4 * 8];
#pragma unroll
    for (int dt = 0; dt < 4; dt++) {
      const bf16x8 bb = *(const bf16x8*)(vb + (size_t)(dt * 16 + l15) * 512 + mk * 32 + l4 * 8);
      o[dt] = __builtin_amdgcn_mfma_f32_16x16x32_bf16(a, bb, o[dt], 0, 0, 0);
    }
  }
  const size_t rbase = (size_t)(b * 2048 + st * 64 + wid * 16 + l4 * 4);
#pragma unroll
  for (int dt = 0; dt < 4; dt++)
#pragma unroll
    for (int i = 0; i < 4; i++)
      aout[(rbase + i) * 768 + h * 64 + dt * 16 + l15] = f2bf(o[dt][i] * rs[i]);
}

extern "C" void kernel_launch(void* const* d_in, const int* in_sizes, int n_in,
                              void* d_out, int out_size, void* d_ws, size_t ws_size,
                              hipStream_t stream) {
  const float* query  = (const float*)d_in[0];
  const float* memory = (const float*)d_in[1];
  const float* mscore = (const float*)d_in[2];
  const float* Wq = (const float*)d_in[3];
  const float* bq = (const float*)d_in[4];
  const float* Wk = (const float*)d_in[5];
  const float* bk = (const float*)d_in[6];
  const float* Wv = (const float*)d_in[7];
  const float* bv = (const float*)d_in[8];
  const float* Wo = (const float*)d_in[9];
  const float* bo = (const float*)d_in[10];
  const float* Wg = (const float*)d_in[11];
  const float* bg = (const float*)d_in[12];
  float* dout = (float*)d_out;

  char* ws = (char*)d_ws;
  unsigned short* concat = (unsigned short*)ws; ws += (size_t)8192 * 1536 * 2;
  unsigned short* mem_bf = (unsigned short*)ws; ws += (size_t)2048 * 768 * 2;
  unsigned short* Wqt = (unsigned short*)ws;    ws += (size_t)768 * 768 * 2;
  unsigned short* Wkt = (unsigned short*)ws;    ws += (size_t)768 * 768 * 2;
  unsigned short* Wvt = (unsigned short*)ws;    ws += (size_t)768 * 768 * 2;
  unsigned short* Wot = (unsigned short*)ws;    ws += (size_t)768 * 768 * 2;
  unsigned short* Wgt = (unsigned short*)ws;    ws += (size_t)768 * 1536 * 2;
  unsigned short* q_bf = (unsigned short*)ws;   ws += (size_t)8192 * 768 * 2;
  unsigned short* k_bf = (unsigned short*)ws;   ws += (size_t)2048 * 768 * 2;
  unsigned short* vT = (unsigned short*)ws;     ws += (size_t)4 * 12 * 64 * 512 * 2;
  unsigned short* attn_bf = (unsigned short*)ws;

  // casts
  k_cast<<<6144, 256, 0, stream>>>(query, concat, 768, 1536, 0, 8192 * 768 / 4);
  k_cast<<<1536, 256, 0, stream>>>(memory, mem_bf, 768, 768, 0, 2048 * 768 / 4);
  // weight transposes (Wt[n][k] = W[k][n])
  k_transpose<<<dim3(24, 24), 256, 0, stream>>>(Wq, Wqt, 768, 768);
  k_transpose<<<dim3(24, 24), 256, 0, stream>>>(Wk, Wkt, 768, 768);
  k_transpose<<<dim3(24, 24), 256, 0, stream>>>(Wv, Wvt, 768, 768);
  k_transpose<<<dim3(24, 24), 256, 0, stream>>>(Wo, Wot, 768, 768);
  k_transpose<<<dim3(24, 48), 256, 0, stream>>>(Wg, Wgt, 1536, 768);
  // projections (q pre-scaled by 1/sqrt(64))
  k_gemm<0><<<dim3(6, 64), 256, 0, stream>>>(concat, 1536, Wqt, 768, bq, 768, 0.125f,
                                             q_bf, nullptr, nullptr, nullptr);
  k_gemm<0><<<dim3(6, 16), 256, 0, stream>>>(mem_bf, 768, Wkt, 768, bk, 768, 1.f,
                                             k_bf, nullptr, nullptr, nullptr);
  k_gemm<1><<<dim3(6, 16), 256, 0, stream>>>(mem_bf, 768, Wvt, 768, bv, 768, 1.f,
                                             vT, nullptr, nullptr, nullptr);
  // attention
  k_attn<<<dim3(32, 12, 4), 256, 0, stream>>>(q_bf, k_bf, vT, mscore, attn_bf);
  // out projection -> concat right half (bf16)
  k_gemm<2><<<dim3(6, 64), 256, 0, stream>>>(attn_bf, 768, Wot, 768, bo, 768, 1.f,
                                             concat, nullptr, nullptr, nullptr);
  // gate GEMM + fused sigmoid mix -> d_out
  k_gemm<3><<<dim3(6, 64), 256, 0, stream>>>(concat, 1536, Wgt, 1536, bg, 1536, 1.f,
                                             nullptr, concat, query, dout);
}

// Round 2
// 211.233 us; speedup vs baseline: 1.4061x; 1.4061x over previous
//
#include <hip/hip_runtime.h>
#include <hip/hip_bf16.h>

#define DEV static __device__ __forceinline__

typedef __attribute__((ext_vector_type(4))) float f32x4;
typedef __attribute__((ext_vector_type(8))) short bf16x8;

DEV unsigned short f2bf(float f) {
  union { float f; unsigned u; } v; v.f = f;
  unsigned r = (v.u + 0x7fffu + ((v.u >> 16) & 1u)) >> 16;
  return (unsigned short)r;
}
DEV float bf2f(unsigned short u) {
  union { unsigned u; float f; } v; v.u = ((unsigned)u) << 16;
  return v.f;
}
DEV void gl_lds16(const unsigned short* g, unsigned short* l) {
  __builtin_amdgcn_global_load_lds(
      (const __attribute__((address_space(1))) void*)g,
      (__attribute__((address_space(3))) void*)l, 16, 0, 0);
}

// ---------------- cast fp32 -> bf16 (optionally into a wider row) ----------
__global__ void k_cast(const float* __restrict__ src, unsigned short* __restrict__ dst,
                       int cols, int ldd, int coloff, int n4) {
  int i = blockIdx.x * 256 + threadIdx.x;
  if (i >= n4) return;
  int idx = i * 4;
  int r = idx / cols, c = idx - r * cols;
  const float4 v = *(const float4*)(src + idx);
  union { unsigned short u[4]; uint2 p; } o;
  o.u[0] = f2bf(v.x); o.u[1] = f2bf(v.y); o.u[2] = f2bf(v.z); o.u[3] = f2bf(v.w);
  *(uint2*)(dst + (size_t)r * ldd + coloff + c) = o.p;
}

// ---------------- transpose + cast: dst[n*K + k] = bf16(src[k*N + n]) ------
__global__ void k_transpose(const float* __restrict__ src, unsigned short* __restrict__ dst,
                            int K, int N) {
  __shared__ float tile[32][33];
  const int n0 = blockIdx.x * 32, k0 = blockIdx.y * 32;
  const int tx = threadIdx.x & 31, ty = threadIdx.x >> 5;
#pragma unroll
  for (int i = 0; i < 4; i++)
    tile[ty + i * 8][tx] = src[(size_t)(k0 + ty + i * 8) * N + n0 + tx];
  __syncthreads();
#pragma unroll
  for (int i = 0; i < 4; i++)
    dst[(size_t)(n0 + ty + i * 8) * K + k0 + tx] = f2bf(tile[tx][ty + i * 8]);
}

// ---------------- GEMM: C[M,768] = A[M,K] @ Bt[768,K]^T + bias -------------
// 128x128 tile, BK=32, 4 waves (2x2), 16x16x32 bf16 MFMA, global_load_lds staging.
template <int EPI>
__global__ void k_gemm(const unsigned short* __restrict__ A, int lda,
                       const unsigned short* __restrict__ Bt, int ldb,
                       const float* __restrict__ bias, int K, float scale,
                       unsigned short* __restrict__ out0,
                       const unsigned short* __restrict__ concat_in,
                       const float* __restrict__ qy, float* __restrict__ dout) {
  __shared__ alignas(16) unsigned short Al[128 * 32];
  __shared__ alignas(16) unsigned short Bl[128 * 32];
  const int t = threadIdx.x;
  const int r0 = blockIdx.y * 128, c0 = blockIdx.x * 128;
  const int lane = t & 63, l15 = lane & 15, l4 = lane >> 4;
  const int wid = t >> 6, wr = wid >> 1, wc = wid & 1;

  f32x4 acc[4][4];
#pragma unroll
  for (int mi = 0; mi < 4; mi++)
#pragma unroll
    for (int ni = 0; ni < 4; ni++) acc[mi][ni] = (f32x4){0.f, 0.f, 0.f, 0.f};

  for (int k0 = 0; k0 < K; k0 += 32) {
#pragma unroll
    for (int p = 0; p < 2; p++) {
      const int flat = (p * 256 + t) * 8;
      const int row = flat >> 5, kk = flat & 31;
      gl_lds16(A + (size_t)(r0 + row) * lda + k0 + kk, &Al[flat]);
      gl_lds16(Bt + (size_t)(c0 + row) * ldb + k0 + kk, &Bl[flat]);
    }
    __syncthreads();
    bf16x8 af[4], bfr[4];
#pragma unroll
    for (int mi = 0; mi < 4; mi++)
      af[mi] = *(const bf16x8*)&Al[(wr * 64 + mi * 16 + l15) * 32 + l4 * 8];
#pragma unroll
    for (int ni = 0; ni < 4; ni++)
      bfr[ni] = *(const bf16x8*)&Bl[(wc * 64 + ni * 16 + l15) * 32 + l4 * 8];
#pragma unroll
    for (int mi = 0; mi < 4; mi++)
#pragma unroll
      for (int ni = 0; ni < 4; ni++)
        acc[mi][ni] = __builtin_amdgcn_mfma_f32_16x16x32_bf16(af[mi], bfr[ni], acc[mi][ni], 0, 0, 0);
    __syncthreads();
  }

#pragma unroll
  for (int ni = 0; ni < 4; ni++) {
    const int c = c0 + wc * 64 + ni * 16 + l15;
    const float bv = bias[c];
#pragma unroll
    for (int mi = 0; mi < 4; mi++) {
      const int rbase = r0 + wr * 64 + mi * 16 + l4 * 4;
#pragma unroll
      for (int i = 0; i < 4; i++) {
        const int r = rbase + i;
        const float val = (acc[mi][ni][i] + bv) * scale;
        if (EPI == 0) {
          out0[(size_t)r * 768 + c] = f2bf(val);
        } else if (EPI == 1) {
          const int b = r >> 9, m = r & 511;
          const int h = c >> 6, dd = c & 63;
          out0[(((size_t)(b * 12 + h)) * 64 + dd) * 512 + m] = f2bf(val);
        } else if (EPI == 2) {
          out0[(size_t)r * 1536 + 768 + c] = f2bf(val);
        } else {
          const float g = 1.f / (1.f + __expf(-val));
          const float o = bf2f(concat_in[(size_t)r * 1536 + 768 + c]);
          const float q = qy[(size_t)r * 768 + c];
          dout[(size_t)r * 768 + c] = g * o + (1.f - g) * q;
        }
      }
    }
  }
}

// ---------------- fused attention (flash-style over M) ---------------------
// grid (32 s-tiles, 12 heads, 4 batch); 4 waves x 16 q-rows; M=512 in 4 chunks
// of 128. K chunk [128x64] and V^T chunk [64x128] staged in LDS (shared by all
// waves) via global_load_lds with XOR-swizzled SOURCE addresses (linear LDS
// dest) to kill the 128B/256B-stride bank pathology on the ds_read_b128 side.
__global__ __launch_bounds__(256, 3) void k_attn(
    const unsigned short* __restrict__ qbf,   // [B*S,768], pre-scaled by 1/8
    const unsigned short* __restrict__ kbf,   // [B*M,768]
    const unsigned short* __restrict__ vT,    // [B,H,64,512]
    const float* __restrict__ mscore,         // [B,512]
    unsigned short* __restrict__ aout) {      // [B*S,768]
  const int st = blockIdx.x, h = blockIdx.y, b = blockIdx.z;
  __shared__ float bias_s[512];
  __shared__ alignas(16) unsigned short Kl[128 * 64];   // 16 KB
  __shared__ alignas(16) unsigned short Vl[64 * 128];   // 16 KB
  __shared__ alignas(16) unsigned short P[4][16][136];  // 17.4 KB
  const int t = threadIdx.x;
  const int wid = t >> 6, lane = t & 63, l15 = lane & 15, l4 = lane >> 4;
  for (int i = t; i < 512; i += 256) bias_s[i] = mscore[b * 512 + i];

  const int srow = st * 64 + wid * 16;
  const unsigned short* qrow = qbf + ((size_t)(b * 2048 + srow + l15)) * 768 + h * 64;
  bf16x8 qa[2];
  qa[0] = *(const bf16x8*)(qrow + l4 * 8);
  qa[1] = *(const bf16x8*)(qrow + 32 + l4 * 8);

  const unsigned short* kbase = kbf + (size_t)(b * 512) * 768 + h * 64;
  const unsigned short* vbase = vT + ((size_t)(b * 12 + h)) * 64 * 512;

  f32x4 O[4];
#pragma unroll
  for (int dt = 0; dt < 4; dt++) O[dt] = (f32x4){0.f, 0.f, 0.f, 0.f};
  float ml[4] = {-1e30f, -1e30f, -1e30f, -1e30f};
  float ll[4] = {0.f, 0.f, 0.f, 0.f};

  for (int ch = 0; ch < 4; ++ch) {
    const int m0 = ch * 128;
    __syncthreads();  // prev chunk fully consumed (and bias_s ready on ch=0)
    // stage K chunk: 128 rows x 8 chunks of 16B; LDS linear, source swizzled
#pragma unroll
    for (int j = 0; j < 4; ++j) {
      const int c = (j * 4 + wid) * 64 + lane;
      const int r = c >> 3, cc = c & 7;
      gl_lds16(kbase + (size_t)(m0 + r) * 768 + ((cc ^ (r & 7)) * 8), &Kl[c * 8]);
    }
    // stage V^T chunk: 64 rows x 16 chunks of 16B
#pragma unroll
    for (int j = 0; j < 4; ++j) {
      const int c = (j * 4 + wid) * 64 + lane;
      const int r = c >> 4, cc = c & 15;
      gl_lds16(vbase + (size_t)r * 512 + m0 + ((cc ^ (r & 7)) * 8), &Vl[c * 8]);
    }
    __syncthreads();  // drains vmcnt (compiler inserts full waitcnt)

    // ---- QK^T for this chunk: scores [16 s x 128 m] per wave
    f32x4 s8[8];
#pragma unroll
    for (int tt = 0; tt < 8; tt++) s8[tt] = (f32x4){0.f, 0.f, 0.f, 0.f};
#pragma unroll
    for (int kb = 0; kb < 2; kb++)
#pragma unroll
      for (int tt = 0; tt < 8; tt++) {
        const int r = tt * 16 + l15;
        const bf16x8 bb = *(const bf16x8*)&Kl[r * 64 + (((kb * 4 + l4) ^ (r & 7)) * 8)];
        s8[tt] = __builtin_amdgcn_mfma_f32_16x16x32_bf16(qa[kb], bb, s8[tt], 0, 0, 0);
      }

    // ---- bias + online softmax update
    float cm[4] = {-3e38f, -3e38f, -3e38f, -3e38f};
#pragma unroll
    for (int tt = 0; tt < 8; tt++) {
      const float bs = bias_s[m0 + tt * 16 + l15];
#pragma unroll
      for (int i = 0; i < 4; i++) {
        s8[tt][i] += bs;
        cm[i] = fmaxf(cm[i], s8[tt][i]);
      }
    }
#pragma unroll
    for (int d = 1; d < 16; d <<= 1)
#pragma unroll
      for (int i = 0; i < 4; i++) cm[i] = fmaxf(cm[i], __shfl_xor(cm[i], d));
    float mn[4], sc[4];
#pragma unroll
    for (int i = 0; i < 4; i++) {
      mn[i] = fmaxf(ml[i], cm[i]);
      sc[i] = __expf(ml[i] - mn[i]);
      ml[i] = mn[i];
      ll[i] *= sc[i];
    }
#pragma unroll
    for (int dt = 0; dt < 4; dt++)
#pragma unroll
      for (int i = 0; i < 4; i++) O[dt][i] *= sc[i];
    float rsum[4] = {0.f, 0.f, 0.f, 0.f};
#pragma unroll
    for (int tt = 0; tt < 8; tt++)
#pragma unroll
      for (int i = 0; i < 4; i++) {
        const float p = __expf(s8[tt][i] - mn[i]);
        rsum[i] += p;
        P[wid][l4 * 4 + i][tt * 16 + l15] = f2bf(p);
      }
#pragma unroll
    for (int d = 1; d < 16; d <<= 1)
#pragma unroll
      for (int i = 0; i < 4; i++) rsum[i] += __shfl_xor(rsum[i], d);
#pragma unroll
    for (int i = 0; i < 4; i++) ll[i] += rsum[i];

    // ---- PV accumulate: O[16 x 64] += P[16 x 128] @ V[128 x 64]
#pragma unroll
    for (int mk = 0; mk < 4; mk++) {
      const bf16x8 pa = *(const bf16x8*)&P[wid][l15][mk * 32 + l4 * 8];
#pragma unroll
      for (int dt = 0; dt < 4; dt++) {
        const int r = dt * 16 + l15;
        const bf16x8 vb = *(const bf16x8*)&Vl[r * 128 + (((mk * 4 + l4) ^ (r & 7)) * 8)];
        O[dt] = __builtin_amdgcn_mfma_f32_16x16x32_bf16(pa, vb, O[dt], 0, 0, 0);
      }
    }
  }

  float rinv[4];
#pragma unroll
  for (int i = 0; i < 4; i++) rinv[i] = 1.f / ll[i];
  const size_t rbase = (size_t)(b * 2048 + srow + l4 * 4);
#pragma unroll
  for (int dt = 0; dt < 4; dt++)
#pragma unroll
    for (int i = 0; i < 4; i++)
      aout[(rbase + i) * 768 + h * 64 + dt * 16 + l15] = f2bf(O[dt][i] * rinv[i]);
}

extern "C" void kernel_launch(void* const* d_in, const int* in_sizes, int n_in,
                              void* d_out, int out_size, void* d_ws, size_t ws_size,
                              hipStream_t stream) {
  const float* query  = (const float*)d_in[0];
  const float* memory = (const float*)d_in[1];
  const float* mscore = (const float*)d_in[2];
  const float* Wq = (const float*)d_in[3];
  const float* bq = (const float*)d_in[4];
  const float* Wk = (const float*)d_in[5];
  const float* bk = (const float*)d_in[6];
  const float* Wv = (const float*)d_in[7];
  const float* bv = (const float*)d_in[8];
  const float* Wo = (const float*)d_in[9];
  const float* bo = (const float*)d_in[10];
  const float* Wg = (const float*)d_in[11];
  const float* bg = (const float*)d_in[12];
  float* dout = (float*)d_out;

  char* ws = (char*)d_ws;
  unsigned short* concat = (unsigned short*)ws; ws += (size_t)8192 * 1536 * 2;
  unsigned short* mem_bf = (unsigned short*)ws; ws += (size_t)2048 * 768 * 2;
  unsigned short* Wqt = (unsigned short*)ws;    ws += (size_t)768 * 768 * 2;
  unsigned short* Wkt = (unsigned short*)ws;    ws += (size_t)768 * 768 * 2;
  unsigned short* Wvt = (unsigned short*)ws;    ws += (size_t)768 * 768 * 2;
  unsigned short* Wot = (unsigned short*)ws;    ws += (size_t)768 * 768 * 2;
  unsigned short* Wgt = (unsigned short*)ws;    ws += (size_t)768 * 1536 * 2;
  unsigned short* q_bf = (unsigned short*)ws;   ws += (size_t)8192 * 768 * 2;
  unsigned short* k_bf = (unsigned short*)ws;   ws += (size_t)2048 * 768 * 2;
  unsigned short* vT = (unsigned short*)ws;     ws += (size_t)4 * 12 * 64 * 512 * 2;
  unsigned short* attn_bf = (unsigned short*)ws;

  // casts
  k_cast<<<6144, 256, 0, stream>>>(query, concat, 768, 1536, 0, 8192 * 768 / 4);
  k_cast<<<1536, 256, 0, stream>>>(memory, mem_bf, 768, 768, 0, 2048 * 768 / 4);
  // weight transposes (Wt[n][k] = W[k][n])
  k_transpose<<<dim3(24, 24), 256, 0, stream>>>(Wq, Wqt, 768, 768);
  k_transpose<<<dim3(24, 24), 256, 0, stream>>>(Wk, Wkt, 768, 768);
  k_transpose<<<dim3(24, 24), 256, 0, stream>>>(Wv, Wvt, 768, 768);
  k_transpose<<<dim3(24, 24), 256, 0, stream>>>(Wo, Wot, 768, 768);
  k_transpose<<<dim3(24, 48), 256, 0, stream>>>(Wg, Wgt, 1536, 768);
  // projections (q pre-scaled by 1/sqrt(64))
  k_gemm<0><<<dim3(6, 64), 256, 0, stream>>>(concat, 1536, Wqt, 768, bq, 768, 0.125f,
                                             q_bf, nullptr, nullptr, nullptr);
  k_gemm<0><<<dim3(6, 16), 256, 0, stream>>>(mem_bf, 768, Wkt, 768, bk, 768, 1.f,
                                             k_bf, nullptr, nullptr, nullptr);
  k_gemm<1><<<dim3(6, 16), 256, 0, stream>>>(mem_bf, 768, Wvt, 768, bv, 768, 1.f,
                                             vT, nullptr, nullptr, nullptr);
  // attention
  k_attn<<<dim3(32, 12, 4), 256, 0, stream>>>(q_bf, k_bf, vT, mscore, attn_bf);
  // out projection -> concat right half (bf16)
  k_gemm<2><<<dim3(6, 64), 256, 0, stream>>>(attn_bf, 768, Wot, 768, bo, 768, 1.f,
                                             concat, nullptr, nullptr, nullptr);
  // gate GEMM + fused sigmoid mix -> d_out
  k_gemm<3><<<dim3(6, 64), 256, 0, stream>>>(concat, 1536, Wgt, 1536, bg, 1536, 1.f,
                                             nullptr, concat, query, dout);
}

// Round 3
// 178.661 us; speedup vs baseline: 1.6625x; 1.1823x over previous
//
#include <hip/hip_runtime.h>
#include <hip/hip_bf16.h>

#define DEV static __device__ __forceinline__

typedef __attribute__((ext_vector_type(4))) float f32x4;
typedef __attribute__((ext_vector_type(8))) short bf16x8;

DEV unsigned short f2bf(float f) {
  union { float f; unsigned u; } v; v.f = f;
  unsigned r = (v.u + 0x7fffu + ((v.u >> 16) & 1u)) >> 16;
  return (unsigned short)r;
}
DEV float bf2f(unsigned short u) {
  union { unsigned u; float f; } v; v.u = ((unsigned)u) << 16;
  return v.f;
}
DEV void gl_lds16(const unsigned short* g, unsigned short* l) {
  __builtin_amdgcn_global_load_lds(
      (const __attribute__((address_space(1))) void*)g,
      (__attribute__((address_space(3))) void*)l, 16, 0, 0);
}

// ---------------- cast fp32 -> bf16 (optionally into a wider row) ----------
__global__ void k_cast(const float* __restrict__ src, unsigned short* __restrict__ dst,
                       int cols, int ldd, int coloff, int n4) {
  int i = blockIdx.x * 256 + threadIdx.x;
  if (i >= n4) return;
  int idx = i * 4;
  int r = idx / cols, c = idx - r * cols;
  const float4 v = *(const float4*)(src + idx);
  union { unsigned short u[4]; uint2 p; } o;
  o.u[0] = f2bf(v.x); o.u[1] = f2bf(v.y); o.u[2] = f2bf(v.z); o.u[3] = f2bf(v.w);
  *(uint2*)(dst + (size_t)r * ldd + coloff + c) = o.p;
}

// ---------------- transpose + cast: dst[n*K + k] = bf16(src[k*N + n]) ------
__global__ void k_transpose(const float* __restrict__ src, unsigned short* __restrict__ dst,
                            int K, int N) {
  __shared__ float tile[32][33];
  const int n0 = blockIdx.x * 32, k0 = blockIdx.y * 32;
  const int tx = threadIdx.x & 31, ty = threadIdx.x >> 5;
#pragma unroll
  for (int i = 0; i < 4; i++)
    tile[ty + i * 8][tx] = src[(size_t)(k0 + ty + i * 8) * N + n0 + tx];
  __syncthreads();
#pragma unroll
  for (int i = 0; i < 4; i++)
    dst[(size_t)(n0 + ty + i * 8) * K + k0 + tx] = f2bf(tile[tx][ty + i * 8]);
}

// ---------------- GEMM: C[M,768] = A[M,K] @ Bt[768,K]^T + bias -------------
// 128x128 tile, BK=32, 4 waves (2x2), 16x16x32 bf16 MFMA.
// Double-buffered LDS + next-tile prefetch (T3 minimum 2-phase) + XCD swizzle.
template <int EPI>
__global__ __launch_bounds__(256) void k_gemm(
    const unsigned short* __restrict__ A, int lda,
    const unsigned short* __restrict__ Bt, int ldb,
    const float* __restrict__ bias, int K, float scale,
    unsigned short* __restrict__ out0,
    const unsigned short* __restrict__ concat_in,
    const float* __restrict__ qy, float* __restrict__ dout, int gx) {
  __shared__ alignas(16) unsigned short Al[2][128 * 32];
  __shared__ alignas(16) unsigned short Bl[2][128 * 32];
  const int t = threadIdx.x;
  // XCD-aware chunked swizzle (requires gridDim.x % 8 == 0 -- all launches obey)
  const int cpx = gridDim.x >> 3;
  const int swz = (blockIdx.x & 7) * cpx + (blockIdx.x >> 3);
  const int r0 = (swz / gx) * 128, c0 = (swz % gx) * 128;
  const int lane = t & 63, l15 = lane & 15, l4 = lane >> 4;
  const int wid = t >> 6, wr = wid >> 1, wc = wid & 1;

#define STAGE(buf, k0)                                                        \
  {                                                                           \
    _Pragma("unroll") for (int p = 0; p < 2; p++) {                           \
      const int flat = (p * 256 + t) * 8;                                     \
      const int row = flat >> 5, kk = flat & 31;                              \
      gl_lds16(A + (size_t)(r0 + row) * lda + (k0) + kk, &Al[buf][flat]);     \
      gl_lds16(Bt + (size_t)(c0 + row) * ldb + (k0) + kk, &Bl[buf][flat]);    \
    }                                                                         \
  }

  f32x4 acc[4][4];
#pragma unroll
  for (int mi = 0; mi < 4; mi++)
#pragma unroll
    for (int ni = 0; ni < 4; ni++) acc[mi][ni] = (f32x4){0.f, 0.f, 0.f, 0.f};

  STAGE(0, 0);
  const int nt = K >> 5;
  for (int tk = 0; tk < nt; ++tk) {
    const int cur = tk & 1;
    // drain own staging stores, then barrier: tile `cur` fully in LDS for all
    // waves AND all waves' reads of buf cur^1 (tile tk-1) are consumed.
    asm volatile("s_waitcnt vmcnt(0)" ::: "memory");
    __builtin_amdgcn_s_barrier();
    if (tk + 1 < nt) STAGE(cur ^ 1, (tk + 1) * 32);  // in flight across compute
    bf16x8 af[4], bfr[4];
#pragma unroll
    for (int mi = 0; mi < 4; mi++)
      af[mi] = *(const bf16x8*)&Al[cur][(wr * 64 + mi * 16 + l15) * 32 + l4 * 8];
#pragma unroll
    for (int ni = 0; ni < 4; ni++)
      bfr[ni] = *(const bf16x8*)&Bl[cur][(wc * 64 + ni * 16 + l15) * 32 + l4 * 8];
#pragma unroll
    for (int mi = 0; mi < 4; mi++)
#pragma unroll
      for (int ni = 0; ni < 4; ni++)
        acc[mi][ni] = __builtin_amdgcn_mfma_f32_16x16x32_bf16(af[mi], bfr[ni], acc[mi][ni], 0, 0, 0);
  }
#undef STAGE

#pragma unroll
  for (int ni = 0; ni < 4; ni++) {
    const int c = c0 + wc * 64 + ni * 16 + l15;
    const float bv = bias[c];
#pragma unroll
    for (int mi = 0; mi < 4; mi++) {
      const int rbase = r0 + wr * 64 + mi * 16 + l4 * 4;
#pragma unroll
      for (int i = 0; i < 4; i++) {
        const int r = rbase + i;
        const float val = (acc[mi][ni][i] + bv) * scale;
        if (EPI == 0) {
          out0[(size_t)r * 768 + c] = f2bf(val);
        } else if (EPI == 1) {
          const int b = r >> 9, m = r & 511;
          const int h = c >> 6, dd = c & 63;
          out0[(((size_t)(b * 12 + h)) * 64 + dd) * 512 + m] = f2bf(val);
        } else if (EPI == 2) {
          out0[(size_t)r * 1536 + 768 + c] = f2bf(val);
        } else {
          const float g = 1.f / (1.f + __expf(-val));
          const float o = bf2f(concat_in[(size_t)r * 1536 + 768 + c]);
          const float q = qy[(size_t)r * 768 + c];
          dout[(size_t)r * 768 + c] = g * o + (1.f - g) * q;
        }
      }
    }
  }
}

// ---------------- fused attention (flash-style over M) ---------------------
__global__ __launch_bounds__(256, 3) void k_attn(
    const unsigned short* __restrict__ qbf,   // [B*S,768], pre-scaled by 1/8
    const unsigned short* __restrict__ kbf,   // [B*M,768]
    const unsigned short* __restrict__ vT,    // [B,H,64,512]
    const float* __restrict__ mscore,         // [B,512]
    unsigned short* __restrict__ aout) {      // [B*S,768]
  const int st = blockIdx.x, h = blockIdx.y, b = blockIdx.z;
  __shared__ float bias_s[512];
  __shared__ alignas(16) unsigned short Kl[128 * 64];   // 16 KB
  __shared__ alignas(16) unsigned short Vl[64 * 128];   // 16 KB
  __shared__ alignas(16) unsigned short P[4][16][136];  // 17.4 KB
  const int t = threadIdx.x;
  const int wid = t >> 6, lane = t & 63, l15 = lane & 15, l4 = lane >> 4;
  for (int i = t; i < 512; i += 256) bias_s[i] = mscore[b * 512 + i];

  const int srow = st * 64 + wid * 16;
  const unsigned short* qrow = qbf + ((size_t)(b * 2048 + srow + l15)) * 768 + h * 64;
  bf16x8 qa[2];
  qa[0] = *(const bf16x8*)(qrow + l4 * 8);
  qa[1] = *(const bf16x8*)(qrow + 32 + l4 * 8);

  const unsigned short* kbase = kbf + (size_t)(b * 512) * 768 + h * 64;
  const unsigned short* vbase = vT + ((size_t)(b * 12 + h)) * 64 * 512;

  f32x4 O[4];
#pragma unroll
  for (int dt = 0; dt < 4; dt++) O[dt] = (f32x4){0.f, 0.f, 0.f, 0.f};
  float ml[4] = {-1e30f, -1e30f, -1e30f, -1e30f};
  float ll[4] = {0.f, 0.f, 0.f, 0.f};

  for (int ch = 0; ch < 4; ++ch) {
    const int m0 = ch * 128;
    __syncthreads();  // prev chunk fully consumed (and bias_s ready on ch=0)
#pragma unroll
    for (int j = 0; j < 4; ++j) {
      const int c = (j * 4 + wid) * 64 + lane;
      const int r = c >> 3, cc = c & 7;
      gl_lds16(kbase + (size_t)(m0 + r) * 768 + ((cc ^ (r & 7)) * 8), &Kl[c * 8]);
    }
#pragma unroll
    for (int j = 0; j < 4; ++j) {
      const int c = (j * 4 + wid) * 64 + lane;
      const int r = c >> 4, cc = c & 15;
      gl_lds16(vbase + (size_t)r * 512 + m0 + ((cc ^ (r & 7)) * 8), &Vl[c * 8]);
    }
    __syncthreads();

    // ---- QK^T for this chunk: scores [16 s x 128 m] per wave
    f32x4 s8[8];
#pragma unroll
    for (int tt = 0; tt < 8; tt++) s8[tt] = (f32x4){0.f, 0.f, 0.f, 0.f};
#pragma unroll
    for (int kb = 0; kb < 2; kb++)
#pragma unroll
      for (int tt = 0; tt < 8; tt++) {
        const int r = tt * 16 + l15;
        const bf16x8 bb = *(const bf16x8*)&Kl[r * 64 + (((kb * 4 + l4) ^ (r & 7)) * 8)];
        s8[tt] = __builtin_amdgcn_mfma_f32_16x16x32_bf16(qa[kb], bb, s8[tt], 0, 0, 0);
      }

    // ---- bias + online softmax update
    float cm[4] = {-3e38f, -3e38f, -3e38f, -3e38f};
#pragma unroll
    for (int tt = 0; tt < 8; tt++) {
      const float bs = bias_s[m0 + tt * 16 + l15];
#pragma unroll
      for (int i = 0; i < 4; i++) {
        s8[tt][i] += bs;
        cm[i] = fmaxf(cm[i], s8[tt][i]);
      }
    }
#pragma unroll
    for (int d = 1; d < 16; d <<= 1)
#pragma unroll
      for (int i = 0; i < 4; i++) cm[i] = fmaxf(cm[i], __shfl_xor(cm[i], d));
    float mn[4], sc[4];
#pragma unroll
    for (int i = 0; i < 4; i++) {
      mn[i] = fmaxf(ml[i], cm[i]);
      sc[i] = __expf(ml[i] - mn[i]);
      ml[i] = mn[i];
      ll[i] *= sc[i];
    }
#pragma unroll
    for (int dt = 0; dt < 4; dt++)
#pragma unroll
      for (int i = 0; i < 4; i++) O[dt][i] *= sc[i];
    float rsum[4] = {0.f, 0.f, 0.f, 0.f};
#pragma unroll
    for (int tt = 0; tt < 8; tt++)
#pragma unroll
      for (int i = 0; i < 4; i++) {
        const float p = __expf(s8[tt][i] - mn[i]);
        rsum[i] += p;
        P[wid][l4 * 4 + i][tt * 16 + l15] = f2bf(p);
      }
#pragma unroll
    for (int d = 1; d < 16; d <<= 1)
#pragma unroll
      for (int i = 0; i < 4; i++) rsum[i] += __shfl_xor(rsum[i], d);
#pragma unroll
    for (int i = 0; i < 4; i++) ll[i] += rsum[i];

    // ---- PV accumulate: O[16 x 64] += P[16 x 128] @ V[128 x 64]
#pragma unroll
    for (int mk = 0; mk < 4; mk++) {
      const bf16x8 pa = *(const bf16x8*)&P[wid][l15][mk * 32 + l4 * 8];
#pragma unroll
      for (int dt = 0; dt < 4; dt++) {
        const int r = dt * 16 + l15;
        const bf16x8 vb = *(const bf16x8*)&Vl[r * 128 + (((mk * 4 + l4) ^ (r & 7)) * 8)];
        O[dt] = __builtin_amdgcn_mfma_f32_16x16x32_bf16(pa, vb, O[dt], 0, 0, 0);
      }
    }
  }

  float rinv[4];
#pragma unroll
  for (int i = 0; i < 4; i++) rinv[i] = 1.f / ll[i];
  const size_t rbase = (size_t)(b * 2048 + srow + l4 * 4);
#pragma unroll
  for (int dt = 0; dt < 4; dt++)
#pragma unroll
    for (int i = 0; i < 4; i++)
      aout[(rbase + i) * 768 + h * 64 + dt * 16 + l15] = f2bf(O[dt][i] * rinv[i]);
}

extern "C" void kernel_launch(void* const* d_in, const int* in_sizes, int n_in,
                              void* d_out, int out_size, void* d_ws, size_t ws_size,
                              hipStream_t stream) {
  const float* query  = (const float*)d_in[0];
  const float* memory = (const float*)d_in[1];
  const float* mscore = (const float*)d_in[2];
  const float* Wq = (const float*)d_in[3];
  const float* bq = (const float*)d_in[4];
  const float* Wk = (const float*)d_in[5];
  const float* bk = (const float*)d_in[6];
  const float* Wv = (const float*)d_in[7];
  const float* bv = (const float*)d_in[8];
  const float* Wo = (const float*)d_in[9];
  const float* bo = (const float*)d_in[10];
  const float* Wg = (const float*)d_in[11];
  const float* bg = (const float*)d_in[12];
  float* dout = (float*)d_out;

  char* ws = (char*)d_ws;
  unsigned short* concat = (unsigned short*)ws; ws += (size_t)8192 * 1536 * 2;
  unsigned short* mem_bf = (unsigned short*)ws; ws += (size_t)2048 * 768 * 2;
  unsigned short* Wqt = (unsigned short*)ws;    ws += (size_t)768 * 768 * 2;
  unsigned short* Wkt = (unsigned short*)ws;    ws += (size_t)768 * 768 * 2;
  unsigned short* Wvt = (unsigned short*)ws;    ws += (size_t)768 * 768 * 2;
  unsigned short* Wot = (unsigned short*)ws;    ws += (size_t)768 * 768 * 2;
  unsigned short* Wgt = (unsigned short*)ws;    ws += (size_t)768 * 1536 * 2;
  unsigned short* q_bf = (unsigned short*)ws;   ws += (size_t)8192 * 768 * 2;
  unsigned short* k_bf = (unsigned short*)ws;   ws += (size_t)2048 * 768 * 2;
  unsigned short* vT = (unsigned short*)ws;     ws += (size_t)4 * 12 * 64 * 512 * 2;
  unsigned short* attn_bf = (unsigned short*)ws;

  // casts
  k_cast<<<6144, 256, 0, stream>>>(query, concat, 768, 1536, 0, 8192 * 768 / 4);
  k_cast<<<1536, 256, 0, stream>>>(memory, mem_bf, 768, 768, 0, 2048 * 768 / 4);
  // weight transposes (Wt[n][k] = W[k][n])
  k_transpose<<<dim3(24, 24), 256, 0, stream>>>(Wq, Wqt, 768, 768);
  k_transpose<<<dim3(24, 24), 256, 0, stream>>>(Wk, Wkt, 768, 768);
  k_transpose<<<dim3(24, 24), 256, 0, stream>>>(Wv, Wvt, 768, 768);
  k_transpose<<<dim3(24, 24), 256, 0, stream>>>(Wo, Wot, 768, 768);
  k_transpose<<<dim3(24, 48), 256, 0, stream>>>(Wg, Wgt, 1536, 768);
  // projections (q pre-scaled by 1/sqrt(64)); grids are 1-D (gx*gy), %8==0
  k_gemm<0><<<6 * 64, 256, 0, stream>>>(concat, 1536, Wqt, 768, bq, 768, 0.125f,
                                        q_bf, nullptr, nullptr, nullptr, 6);
  k_gemm<0><<<6 * 16, 256, 0, stream>>>(mem_bf, 768, Wkt, 768, bk, 768, 1.f,
                                        k_bf, nullptr, nullptr, nullptr, 6);
  k_gemm<1><<<6 * 16, 256, 0, stream>>>(mem_bf, 768, Wvt, 768, bv, 768, 1.f,
                                        vT, nullptr, nullptr, nullptr, 6);
  // attention
  k_attn<<<dim3(32, 12, 4), 256, 0, stream>>>(q_bf, k_bf, vT, mscore, attn_bf);
  // out projection -> concat right half (bf16)
  k_gemm<2><<<6 * 64, 256, 0, stream>>>(attn_bf, 768, Wot, 768, bo, 768, 1.f,
                                        concat, nullptr, nullptr, nullptr, 6);
  // gate GEMM + fused sigmoid mix -> d_out
  k_gemm<3><<<6 * 64, 256, 0, stream>>>(concat, 1536, Wgt, 1536, bg, 1536, 1.f,
                                        nullptr, concat, query, dout, 6);
}